// Round 3
// baseline (713.133 us; speedup 1.0000x reference)
//
#include <hip/hip_runtime.h>

typedef short bf16x8 __attribute__((ext_vector_type(8)));
typedef float f32x4 __attribute__((ext_vector_type(4)));

constexpr int N_NODES = 50000;
constexpr int F_IN    = 512;
constexpr int F_HID   = 256;
constexpr int F_OUT   = 40;
constexpr int SCAN_BLOCKS = (N_NODES + 255) / 256;   // 196

__device__ __forceinline__ float bf2f(unsigned short u) {
  return __uint_as_float(((unsigned)u) << 16);
}
__device__ __forceinline__ unsigned short f2bf(float f) {
  unsigned x = __float_as_uint(f);
  x += 0x7FFFu + ((x >> 16) & 1u);      // RNE
  return (unsigned short)(x >> 16);
}

// pack 8 fp32 -> bf16x8 (RNE)
__device__ __forceinline__ bf16x8 cvt8(f32x4 a, f32x4 b) {
  bf16x8 o;
  o[0] = (short)f2bf(a[0]); o[1] = (short)f2bf(a[1]);
  o[2] = (short)f2bf(a[2]); o[3] = (short)f2bf(a[3]);
  o[4] = (short)f2bf(b[0]); o[5] = (short)f2bf(b[1]);
  o[6] = (short)f2bf(b[2]); o[7] = (short)f2bf(b[3]);
  return o;
}

// JAX threefry2x32, key=(0,42), PARTITIONABLE counter scheme (verified R8):
// element i -> pair (0, i); output = x0_final ^ x1_final; keep iff bit31==0.
__device__ __forceinline__ unsigned tf_rotl(unsigned x, int d) {
  return (x << d) | (x >> (32 - d));
}
__device__ __forceinline__ unsigned threefry_bits(unsigned i) {
  const unsigned k0 = 0u, k1 = 42u, k2 = 0x1BD11BDAu ^ 0u ^ 42u;
  unsigned x0 = 0u + k0, x1 = i + k1;
#define TF_R(r) { x0 += x1; x1 = tf_rotl(x1, (r)) ^ x0; }
  TF_R(13) TF_R(15) TF_R(26) TF_R(6)   x0 += k1; x1 += k2 + 1u;
  TF_R(17) TF_R(29) TF_R(16) TF_R(24)  x0 += k2; x1 += k0 + 2u;
  TF_R(13) TF_R(15) TF_R(26) TF_R(6)   x0 += k0; x1 += k1 + 3u;
  TF_R(17) TF_R(29) TF_R(16) TF_R(24)  x0 += k1; x1 += k2 + 4u;
  TF_R(13) TF_R(15) TF_R(26) TF_R(6)   x0 += k2; x1 += k0 + 5u;
#undef TF_R
  return x0 ^ x1;
}

__global__ void k_zero(int* __restrict__ p, int n) {
  int i = blockIdx.x * 256 + threadIdx.x;
  if (i < n) p[i] = 0;
}

// ---------------- CSR build ----------------
__global__ void k_hist(const int* __restrict__ dst, int* __restrict__ deg, int E) {
  int e = blockIdx.x * 256 + threadIdx.x;
  if (e < E) atomicAdd(&deg[dst[e]], 1);
}

// Parallel 3-stage scan.
__global__ __launch_bounds__(256) void k_scan_part(const int* __restrict__ deg,
                                                   int* __restrict__ bsum) {
  __shared__ int red[256];
  int t = threadIdx.x;
  int i = blockIdx.x * 256 + t;
  red[t] = (i < N_NODES) ? deg[i] : 0;
  __syncthreads();
#pragma unroll
  for (int off = 128; off > 0; off >>= 1) {
    if (t < off) red[t] += red[t + off];
    __syncthreads();
  }
  if (t == 0) bsum[blockIdx.x] = red[0];
}

__global__ __launch_bounds__(256) void k_scan_base(int* __restrict__ bsum,
                                                   int* __restrict__ offs) {
  __shared__ int sh[256];
  int t = threadIdx.x;
  int v = (t < SCAN_BLOCKS) ? bsum[t] : 0;
  sh[t] = v;
  __syncthreads();
#pragma unroll
  for (int off = 1; off < 256; off <<= 1) {
    int x = (t >= off) ? sh[t - off] : 0;
    __syncthreads();
    sh[t] += x;
    __syncthreads();
  }
  if (t < SCAN_BLOCKS) bsum[t] = sh[t] - v;        // exclusive block base
  if (t == 255) offs[N_NODES] = sh[255];           // == E
}

__global__ __launch_bounds__(256) void k_scan_final(int* __restrict__ deg,
                                                    const int* __restrict__ bsum,
                                                    int* __restrict__ offs) {
  __shared__ int sh[256];
  int t = threadIdx.x;
  int i = blockIdx.x * 256 + t;
  int v = (i < N_NODES) ? deg[i] : 0;
  sh[t] = v;
  __syncthreads();
#pragma unroll
  for (int off = 1; off < 256; off <<= 1) {
    int x = (t >= off) ? sh[t - off] : 0;
    __syncthreads();
    sh[t] += x;
    __syncthreads();
  }
  if (i < N_NODES) {
    offs[i] = bsum[blockIdx.x] + sh[t] - v;        // exclusive
    deg[i] = 0;                                    // becomes scatter cursor
  }
}

// packed edge: (src << 16) | bf16(weight)
__global__ void k_scatter(const int* __restrict__ src, const int* __restrict__ dst,
                          const float* __restrict__ w,
                          const int* __restrict__ offs, int* __restrict__ cursor,
                          unsigned* __restrict__ ep, int E) {
  int e = blockIdx.x * 256 + threadIdx.x;
  if (e < E) {
    int d = dst[e];
    int pos = offs[d] + atomicAdd(&cursor[d], 1);
    if (pos >= 0 && pos < E)
      ep[pos] = ((unsigned)src[e] << 16) | (unsigned)f2bf(w[e]);
  }
}

// ---------------- W1 -> bf16 transpose: wT[c][k] = bf16(W1[k][c]) -------------
__global__ void k_wt(const float* __restrict__ W1, unsigned short* __restrict__ wT) {
  int i = blockIdx.x * 256 + threadIdx.x;      // 131072 elements
  if (i < F_IN * F_HID) {
    int c = i >> 9, k = i & 511;
    wT[i] = f2bf(W1[(size_t)k * F_HID + c]);
  }
}

// ---------------- layer-1 MFMA GEMM half: h1h = x @ W1[:, half*128 .. +128) ---
// LDS-free + ping-pong register B buffers: 8 B-fragment loads stay in flight
// (BA/BB alternate) while MFMAs consume the previously loaded 8. X loaded
// direct per-lane (coalesced, each row owned by one wave). K-loop fully
// unrolled so the last-iteration guard is static.
__global__ __launch_bounds__(256) void k_gemm1m(const float* __restrict__ X,
                                                const unsigned short* __restrict__ wT,
                                                unsigned short* __restrict__ h1h,
                                                int half) {
  int t = threadIdx.x;
  int wave = t >> 6, lane = t & 63, q = lane >> 4, r = lane & 15;
  int r0 = blockIdx.x * 64;
  int arow = r0 + wave * 16 + r;               // this lane's A row
  if (arow > N_NODES - 1) arow = N_NODES - 1;  // clamp (results discarded)
  const float* xrow = X + (size_t)arow * F_IN + q * 8;
  const unsigned short* bl = wT + (size_t)half * 128 * F_IN + (size_t)r * F_IN + q * 8;
  f32x4 acc[8];
#pragma unroll
  for (int n = 0; n < 8; ++n) acc[n] = (f32x4){0.f, 0.f, 0.f, 0.f};

  bf16x8 BA[8], BB[8];
#pragma unroll
  for (int n = 0; n < 8; ++n)
    BA[n] = *(const bf16x8*)(bl + (size_t)n * 16 * F_IN);

#pragma unroll
  for (int k0 = 0; k0 < F_IN; k0 += 64) {
    f32x4 a0 = *(const f32x4*)(xrow + k0);
    f32x4 a1 = *(const f32x4*)(xrow + k0 + 4);
    f32x4 a2 = *(const f32x4*)(xrow + k0 + 32);
    f32x4 a3 = *(const f32x4*)(xrow + k0 + 36);
    bf16x8 A0 = cvt8(a0, a1);
    bf16x8 A1 = cvt8(a2, a3);
    // issue loads for the second K-chunk of this k0
#pragma unroll
    for (int n = 0; n < 8; ++n)
      BB[n] = *(const bf16x8*)(bl + (size_t)n * 16 * F_IN + k0 + 32);
    // consume BA (chunk kc=0) while BB is in flight
#pragma unroll
    for (int n = 0; n < 8; ++n)
      acc[n] = __builtin_amdgcn_mfma_f32_16x16x32_bf16(A0, BA[n], acc[n], 0, 0, 0);
    // issue loads for the next k0's first chunk while BB is consumed
    if (k0 + 64 < F_IN) {
#pragma unroll
      for (int n = 0; n < 8; ++n)
        BA[n] = *(const bf16x8*)(bl + (size_t)n * 16 * F_IN + k0 + 64);
    }
#pragma unroll
    for (int n = 0; n < 8; ++n)
      acc[n] = __builtin_amdgcn_mfma_f32_16x16x32_bf16(A1, BB[n], acc[n], 0, 0, 0);
  }
  // D: col = n*16 + r, row = wave*16 + q*4 + tt  (verified layout)
  int mrow = r0 + wave * 16 + q * 4;
#pragma unroll
  for (int n = 0; n < 8; ++n) {
#pragma unroll
    for (int tt = 0; tt < 4; ++tt) {
      int row = mrow + tt;
      if (row < N_NODES) h1h[(size_t)row * 128 + n * 16 + r] = f2bf(acc[n][tt]);
    }
  }
}

// ---------------- fused agg1-half + gemm2-half (o1 accumulates) ---------------
// 2 edges per wave-gather: lanes 0-31 take even edges, 32-63 odd edges; each
// lane loads ushort4 (4 cols). Halves gather VMEM instructions + addr VALU
// vs the ushort2-per-edge version. Parities combined via shfl_xor(32).
__global__ __launch_bounds__(256) void k_agg1h(const unsigned short* __restrict__ h1h,
                                               const int* __restrict__ offs,
                                               const unsigned* __restrict__ ep,
                                               const float* __restrict__ b1,
                                               const float* __restrict__ W2,
                                               float* __restrict__ o1, int half) {
  __shared__ unsigned short w2h[128 * F_OUT];  // 10 KB
  __shared__ float hrow[4][128];               // 2 KB
  int t = threadIdx.x;
  for (int i = t; i < 128 * F_OUT; i += 256) {
    int k = i / F_OUT, j = i - k * F_OUT;
    w2h[i] = f2bf(W2[(size_t)(half * 128 + k) * F_OUT + j]);
  }
  int wave = t >> 6, lane = t & 63;
  int sub = lane >> 5, j = lane & 31;
  int wid = blockIdx.x * 4 + wave;
  int s0 = offs[wid], s1 = offs[wid + 1];
  float a0 = 0.f, a1 = 0.f, a2 = 0.f, a3 = 0.f;
  const unsigned short* hb = h1h + (size_t)j * 4;     // this lane's col group
  int e = s0;
  for (; e + 4 <= s1; e += 4) {
    unsigned p0 = ep[e], p1 = ep[e + 1], p2 = ep[e + 2], p3 = ep[e + 3];
    unsigned pa = sub ? p1 : p0;
    unsigned pb = sub ? p3 : p2;
    ushort4 va = *(const ushort4*)(hb + (size_t)(pa >> 16) * 128);
    ushort4 vb = *(const ushort4*)(hb + (size_t)(pb >> 16) * 128);
    float wa = bf2f((unsigned short)pa);
    float wb = bf2f((unsigned short)pb);
    a0 = fmaf(wa, bf2f(va.x), a0); a1 = fmaf(wa, bf2f(va.y), a1);
    a2 = fmaf(wa, bf2f(va.z), a2); a3 = fmaf(wa, bf2f(va.w), a3);
    a0 = fmaf(wb, bf2f(vb.x), a0); a1 = fmaf(wb, bf2f(vb.y), a1);
    a2 = fmaf(wb, bf2f(vb.z), a2); a3 = fmaf(wb, bf2f(vb.w), a3);
  }
  if (e + 2 <= s1) {
    unsigned p0 = ep[e], p1 = ep[e + 1];
    unsigned pa = sub ? p1 : p0;
    ushort4 va = *(const ushort4*)(hb + (size_t)(pa >> 16) * 128);
    float wa = bf2f((unsigned short)pa);
    a0 = fmaf(wa, bf2f(va.x), a0); a1 = fmaf(wa, bf2f(va.y), a1);
    a2 = fmaf(wa, bf2f(va.z), a2); a3 = fmaf(wa, bf2f(va.w), a3);
    e += 2;
  }
  if (e < s1) {                                // odd single leftover
    unsigned pe = ep[e];
    float wa = sub ? 0.f : bf2f((unsigned short)pe);   // only sub0 contributes
    ushort4 va = *(const ushort4*)(hb + (size_t)(pe >> 16) * 128);
    a0 = fmaf(wa, bf2f(va.x), a0); a1 = fmaf(wa, bf2f(va.y), a1);
    a2 = fmaf(wa, bf2f(va.z), a2); a3 = fmaf(wa, bf2f(va.w), a3);
  }
  // combine the two parity halves (lane l <-> l^32)
  a0 += __shfl_xor(a0, 32, 64);
  a1 += __shfl_xor(a1, 32, 64);
  a2 += __shfl_xor(a2, 32, 64);
  a3 += __shfl_xor(a3, 32, 64);
  if (sub == 0) {
    float av0 = a0, av1 = a1, av2 = a2, av3 = a3;
    int c0 = j * 4;
    int gc = half * 128 + c0;
    unsigned base = (unsigned)wid * 256u + (unsigned)gc;
    float r0 = fmaxf(av0 + b1[gc + 0], 0.f);
    float r1 = fmaxf(av1 + b1[gc + 1], 0.f);
    float r2 = fmaxf(av2 + b1[gc + 2], 0.f);
    float r3 = fmaxf(av3 + b1[gc + 3], 0.f);
    hrow[wave][c0 + 0] = (threefry_bits(base + 0u) >> 31) ? 0.f : r0 * 2.f;
    hrow[wave][c0 + 1] = (threefry_bits(base + 1u) >> 31) ? 0.f : r1 * 2.f;
    hrow[wave][c0 + 2] = (threefry_bits(base + 2u) >> 31) ? 0.f : r2 * 2.f;
    hrow[wave][c0 + 3] = (threefry_bits(base + 3u) >> 31) ? 0.f : r3 * 2.f;
  }
  __syncthreads();                             // w2h + hrow visibility
  if (lane < F_OUT) {
    float acc = 0.f;
#pragma unroll 8
    for (int k = 0; k < 128; ++k)
      acc = fmaf(hrow[wave][k], bf2f(w2h[k * F_OUT + lane]), acc);
    o1[(size_t)wid * F_OUT + lane] += acc;
  }
}

// ---------------- agg2: out[d] = sum_e w*o1[src] + b2 (fp32 out) --------------
__global__ __launch_bounds__(256) void k_agg2(const float* __restrict__ o1,
                                              const int* __restrict__ offs,
                                              const unsigned* __restrict__ ep,
                                              const float* __restrict__ b2,
                                              float* __restrict__ out) {
  int wid  = (blockIdx.x << 2) + (threadIdx.x >> 6);
  int lane = threadIdx.x & 63;
  if (lane >= F_OUT) return;
  int s0 = offs[wid], s1 = offs[wid + 1];
  float acc = 0.f;
  int e = s0;
  for (; e + 4 <= s1; e += 4) {
    unsigned p0 = ep[e], p1 = ep[e + 1], p2 = ep[e + 2], p3 = ep[e + 3];
    float g0 = o1[(size_t)(p0 >> 16) * F_OUT + lane];
    float g1 = o1[(size_t)(p1 >> 16) * F_OUT + lane];
    float g2 = o1[(size_t)(p2 >> 16) * F_OUT + lane];
    float g3 = o1[(size_t)(p3 >> 16) * F_OUT + lane];
    acc = fmaf(bf2f((unsigned short)p0), g0, acc);
    acc = fmaf(bf2f((unsigned short)p1), g1, acc);
    acc = fmaf(bf2f((unsigned short)p2), g2, acc);
    acc = fmaf(bf2f((unsigned short)p3), g3, acc);
  }
  for (; e < s1; ++e) {
    unsigned pe = ep[e];
    acc = fmaf(bf2f((unsigned short)pe), o1[(size_t)(pe >> 16) * F_OUT + lane], acc);
  }
  out[(size_t)wid * F_OUT + lane] = acc + b2[lane];
}

extern "C" void kernel_launch(void* const* d_in, const int* in_sizes, int n_in,
                              void* d_out, int out_size, void* d_ws, size_t ws_size,
                              hipStream_t stream) {
  const float* x    = (const float*)d_in[0];
  const int*   esrc = (const int*)d_in[1];
  const int*   edst = (const int*)d_in[2];
  const float* ew   = (const float*)d_in[3];
  const float* W1   = (const float*)d_in[4];
  const float* b1   = (const float*)d_in[5];
  const float* W2   = (const float*)d_in[6];
  const float* b2   = (const float*)d_in[7];
  const int E = in_sizes[1];

  // workspace ~27.9 MB (<= verified budget)
  char* p = (char*)d_ws;
  auto alloc = [&](size_t bytes) { char* r = p; p += (bytes + 255) & ~(size_t)255; return r; };
  unsigned short* h1h  = (unsigned short*)alloc((size_t)N_NODES * 128 * 2); // 12.8 MB
  float*          o1   = (float*)alloc((size_t)N_NODES * F_OUT * 4);        // 8 MB
  unsigned*       ep   = (unsigned*)alloc((size_t)E * 4);                   // 6.4 MB
  unsigned short* wT   = (unsigned short*)alloc((size_t)F_IN * F_HID * 2);  // 262 KB
  int*            offs = (int*)alloc((size_t)(N_NODES + 1) * 4);
  int*            deg  = (int*)alloc((size_t)N_NODES * 4);
  int*            bsum = (int*)alloc((size_t)SCAN_BLOCKS * 4);

  int eb = (E + 255) / 256;
  k_zero<<<(N_NODES + 255) / 256, 256, 0, stream>>>(deg, N_NODES);
  k_zero<<<(N_NODES * F_OUT + 255) / 256, 256, 0, stream>>>((int*)o1, N_NODES * F_OUT);
  k_wt<<<(F_IN * F_HID + 255) / 256, 256, 0, stream>>>(W1, wT);
  k_hist<<<eb, 256, 0, stream>>>(edst, deg, E);
  k_scan_part<<<SCAN_BLOCKS, 256, 0, stream>>>(deg, bsum);
  k_scan_base<<<1, 256, 0, stream>>>(bsum, offs);
  k_scan_final<<<SCAN_BLOCKS, 256, 0, stream>>>(deg, bsum, offs);
  k_scatter<<<eb, 256, 0, stream>>>(esrc, edst, ew, offs, deg, ep, E);

  int gblocks = (N_NODES + 63) / 64;           // 782
  for (int half = 0; half < 2; ++half) {
    k_gemm1m<<<gblocks, 256, 0, stream>>>(x, wT, h1h, half);
    k_agg1h<<<N_NODES / 4, 256, 0, stream>>>(h1h, offs, ep, b1, W2, o1, half);
  }
  k_agg2<<<N_NODES / 4, 256, 0, stream>>>(o1, offs, ep, b2, (float*)d_out);
}